// Round 2
// baseline (280.808 us; speedup 1.0000x reference)
//
#include <hip/hip_runtime.h>

#define OUTDIM 512
#define ROWS_PER_BLOCK 64
#define ITERS (ROWS_PER_BLOCK / 2)   // 32 rows per thread (even/odd split across wave pairs)

typedef float vf4 __attribute__((ext_vector_type(4)));

__device__ __forceinline__ float rbf_one(float x0, float x1, float x2,
                                         float c0, float c1, float c2,
                                         float w3) {
    float dx = x0 - c0;
    float dy = x1 - c1;
    float dz = x2 - c2;
    float s  = fmaf(dz, dz, fmaf(dy, dy, dx * dx));   // s = d^2
    float d  = sqrtf(s);
    // 35 d^2 + 18 d + 3 == fmaf(d, 18, fmaf(s, 35, 3)); the s-half overlaps sqrt latency
    float pa = fmaf(s, 35.0f, 3.0f);
    float p  = fmaf(d, 18.0f, pa);
    float t  = 1.0f - d;
    float t2 = t * t;
    float t4 = t2 * t2;
    float t6 = t4 * t2;
    return t6 * (p * w3);
}

__global__ __launch_bounds__(256) void rbf_kernel(const float* __restrict__ x,
                                                  const float* __restrict__ centers,
                                                  const float* __restrict__ weights,
                                                  float* __restrict__ out,
                                                  int B) {
    const int tid = threadIdx.x;
    const int q   = tid & 127;   // column quad: columns [4q, 4q+4)
    const int r2  = tid >> 7;    // 0 or 1: which row-parity this wave-pair handles
    const int rb  = blockIdx.x * ROWS_PER_BLOCK;

    // ---- per-thread centers (AoS: 12 contiguous floats) + 4 weights, loaded ONCE
    //      and now amortized over 32 output rows instead of 8 ----
    const vf4* cp4 = (const vf4*)(centers + q * 12);
    const vf4 ca = cp4[0];
    const vf4 cb = cp4[1];
    const vf4 cc = cp4[2];
    // center o=4q+0: (ca.x, ca.y, ca.z)
    // center o=4q+1: (ca.w, cb.x, cb.y)
    // center o=4q+2: (cb.z, cb.w, cc.x)
    // center o=4q+3: (cc.y, cc.z, cc.w)
    const vf4 wv = *(const vf4*)(weights + q * 4);
    const float w30 = wv.x * (1.0f / 3.0f);
    const float w31 = wv.y * (1.0f / 3.0f);
    const float w32 = wv.z * (1.0f / 3.0f);
    const float w33 = wv.w * (1.0f / 3.0f);

    // ---- x rows: wave-uniform index (tid>>7 constant per 64-lane wave) forced
    //      through readfirstlane -> s_load into SGPRs. 2-deep rotating prefetch:
    //      row for iter rr is loaded at iter rr-2, hiding scalar-cache latency. ----
    const int xoff = __builtin_amdgcn_readfirstlane((rb + r2) * 3);

    float a0 = x[xoff + 0], a1 = x[xoff + 1], a2 = x[xoff + 2];   // row rr=0
    float b0 = x[xoff + 6], b1 = x[xoff + 7], b2 = x[xoff + 8];   // row rr=1

    float* outp = out + (size_t)(rb + r2) * OUTDIM + q * 4;

#pragma unroll 4
    for (int rr = 0; rr < ITERS; ++rr) {
        const float x0 = a0, x1 = a1, x2 = a2;
        a0 = b0; a1 = b1; a2 = b2;
        // prefetch row rr+2 (clamped on the last two iters -> harmless re-read)
        const int pr = (rr + 2 < ITERS) ? (rr + 2) : (ITERS - 1);
        const int ib = xoff + pr * 6;
        b0 = x[ib + 0]; b1 = x[ib + 1]; b2 = x[ib + 2];

        vf4 res;
        res.x = rbf_one(x0, x1, x2, ca.x, ca.y, ca.z, w30);
        res.y = rbf_one(x0, x1, x2, ca.w, cb.x, cb.y, w31);
        res.z = rbf_one(x0, x1, x2, cb.z, cb.w, cc.x, w32);
        res.w = rbf_one(x0, x1, x2, cc.y, cc.z, cc.w, w33);

        // pure streaming output, never re-read in-kernel -> nontemporal store
        __builtin_nontemporal_store(res, (vf4*)outp);
        outp += 2 * OUTDIM;   // next row of this parity
    }
}

extern "C" void kernel_launch(void* const* d_in, const int* in_sizes, int n_in,
                              void* d_out, int out_size, void* d_ws, size_t ws_size,
                              hipStream_t stream) {
    const float* x       = (const float*)d_in[0];
    const float* centers = (const float*)d_in[1];
    const float* weights = (const float*)d_in[2];
    float*       out     = (float*)d_out;

    const int B = in_sizes[0] / 3;   // 131072 (multiple of 64 -> no tail handling needed)
    const int blocks = (B + ROWS_PER_BLOCK - 1) / ROWS_PER_BLOCK;  // 2048

    hipLaunchKernelGGL(rbf_kernel, dim3(blocks), dim3(256), 0, stream,
                       x, centers, weights, out, B);
}

// Round 3
// 267.119 us; speedup vs baseline: 1.0512x; 1.0512x over previous
//
#include <hip/hip_runtime.h>

#define OUTDIM 512
#define ROWS_PER_BLOCK 64
#define HALF (ROWS_PER_BLOCK / 2)   // 32 contiguous rows per wave-pair
#define BATCH 8                     // rows computed per prefetch batch
#define NBATCH (HALF / BATCH)       // 4

typedef float vf4 __attribute__((ext_vector_type(4)));

__device__ __forceinline__ float rbf_one(float x0, float x1, float x2,
                                         float c0, float c1, float c2,
                                         float w3) {
    float dx = x0 - c0;
    float dy = x1 - c1;
    float dz = x2 - c2;
    float s  = fmaf(dz, dz, fmaf(dy, dy, dx * dx));   // s = d^2
    float d  = sqrtf(s);
    // 35 d^2 + 18 d + 3 == fmaf(d, 18, fmaf(s, 35, 3)); the s-half overlaps sqrt latency
    float pa = fmaf(s, 35.0f, 3.0f);
    float p  = fmaf(d, 18.0f, pa);
    float t  = 1.0f - d;
    float t2 = t * t;
    float t4 = t2 * t2;
    float t6 = t4 * t2;
    return t6 * (p * w3);
}

// element i (compile-time after unroll) of a vf4 array viewed as flat floats
__device__ __forceinline__ float xel(const vf4* v, int i) {
    return v[i >> 2][i & 3];
}

__global__ __launch_bounds__(256) void rbf_kernel(const float* __restrict__ x,
                                                  const float* __restrict__ centers,
                                                  const float* __restrict__ weights,
                                                  float* __restrict__ out,
                                                  int B) {
    const int tid = threadIdx.x;
    const int q   = tid & 127;   // column quad: columns [4q, 4q+4)
    const int r2  = tid >> 7;    // 0 or 1: which contiguous 32-row half this wave-pair owns
    const int rb  = blockIdx.x * ROWS_PER_BLOCK + r2 * HALF;

    // ---- per-thread centers (AoS: 12 contiguous floats) + 4 weights, loaded ONCE,
    //      amortized over 32 output rows ----
    const vf4* cp4 = (const vf4*)(centers + q * 12);
    const vf4 ca = cp4[0];
    const vf4 cb = cp4[1];
    const vf4 cc = cp4[2];
    // center o=4q+0: (ca.x, ca.y, ca.z)
    // center o=4q+1: (ca.w, cb.x, cb.y)
    // center o=4q+2: (cb.z, cb.w, cc.x)
    // center o=4q+3: (cc.y, cc.z, cc.w)
    const vf4 wv = *(const vf4*)(weights + q * 4);
    const float w30 = wv.x * (1.0f / 3.0f);
    const float w31 = wv.y * (1.0f / 3.0f);
    const float w32 = wv.z * (1.0f / 3.0f);
    const float w33 = wv.w * (1.0f / 3.0f);

    // ---- x rows: wave-uniform base (tid>>7 constant per 64-lane wave) forced through
    //      readfirstlane -> s_load_dwordx4 batches into SGPRs. Software double-buffer:
    //      batch b+1's 6 scalar vec-loads issue BEFORE batch b's 8 independent
    //      compute iterations, hiding scalar-cache latency under ~1000 cyc of VALU. ----
    const int xbase = __builtin_amdgcn_readfirstlane(rb * 3);
    const vf4* xp4  = (const vf4*)(x + xbase);   // rb*3 multiple of 96 -> 16B-aligned

    vf4 bufA[6], bufB[6];
#pragma unroll
    for (int i = 0; i < 6; ++i) bufA[i] = xp4[i];

    float* outp = out + (size_t)rb * OUTDIM + q * 4;

#pragma unroll
    for (int b = 0; b < NBATCH; ++b) {
        if (b + 1 < NBATCH) {
#pragma unroll
            for (int i = 0; i < 6; ++i) bufB[i] = xp4[(b + 1) * 6 + i];
        }

#pragma unroll
        for (int j = 0; j < BATCH; ++j) {
            const float x0 = xel(bufA, 3 * j + 0);
            const float x1 = xel(bufA, 3 * j + 1);
            const float x2 = xel(bufA, 3 * j + 2);

            vf4 res;
            res.x = rbf_one(x0, x1, x2, ca.x, ca.y, ca.z, w30);
            res.y = rbf_one(x0, x1, x2, ca.w, cb.x, cb.y, w31);
            res.z = rbf_one(x0, x1, x2, cb.z, cb.w, cc.x, w32);
            res.w = rbf_one(x0, x1, x2, cc.y, cc.z, cc.w, w33);

            // pure streaming output, never re-read in-kernel -> nontemporal store
            __builtin_nontemporal_store(res, (vf4*)outp);
            outp += OUTDIM;
        }

#pragma unroll
        for (int i = 0; i < 6; ++i) bufA[i] = bufB[i];   // SSA-renamed away after full unroll
    }
}

extern "C" void kernel_launch(void* const* d_in, const int* in_sizes, int n_in,
                              void* d_out, int out_size, void* d_ws, size_t ws_size,
                              hipStream_t stream) {
    const float* x       = (const float*)d_in[0];
    const float* centers = (const float*)d_in[1];
    const float* weights = (const float*)d_in[2];
    float*       out     = (float*)d_out;

    const int B = in_sizes[0] / 3;   // 131072 (multiple of 64 -> no tail handling needed)
    const int blocks = (B + ROWS_PER_BLOCK - 1) / ROWS_PER_BLOCK;  // 2048

    hipLaunchKernelGGL(rbf_kernel, dim3(blocks), dim3(256), 0, stream,
                       x, centers, weights, out, B);
}